// Round 5
// baseline (127.373 us; speedup 1.0000x reference)
//
#include <hip/hip_runtime.h>
#include <hip/hip_cooperative_groups.h>

namespace cg = cooperative_groups;

#define T_FRAMES 2048
#define D_DIM    1024
#define V_DIM    28
#define BSTRIDE  32                 // Bmat row stride (padded, pow2)
#define CSTRIDE  32                 // cpart row stride (padded, pow2)
#define LOG2E_F  1.44269504088896f

#define CHUNK    8                  // stored steps per scan block
#define WARM     24                 // warm-up steps (contraction ~0.28^24 ~ 5e-14)
#define NBLK     256                // grid: 1 block/CU, coop co-resident
#define RPB      8                  // x rows per block (512 thr = 8 waves = 2/SIMD)

// ---------------------------------------------------------------------------
// Single cooperative kernel (was 2 dispatches; saves one dependent-dispatch
// gap ~2us and lets the scan wave preload Wo regs before the grid sync).
//
// Phase 1 (prep), 256 blocks x 512 threads, block b owns x rows 8b..8b+7:
//   - stage 8 rows in LDS (32 KB) while folding the block-partial colsum
//     (x read ONCE: 8 MB),
//   - cpart[b][i] = Co[i,:] . partial_colsum  (b-major, stride 32, pads
//     zeroed; scan finishes c in DOUBLE — R3's fp32 finish cost absmax 4e-3),
//   - Bmat[8b+r+1][i] = (Uo[i,:] . x[8b+r]) * log2e. Waves 0-3 hold 4
//     Uo rows in regs, waves 4-7 hold 3 (28 total), reused across 8 x-rows:
//     Uo+Co L2 traffic 256 x 229 KB = 59 MB (R4: 115 MB) at the SAME
//     2 waves/SIMD TLP (R2's 1 wave/SIMD at RPB=8/256thr was latency-bound).
//
// grid.sync()  [hipLaunchCooperativeKernel; 256 blocks x 512 thr x <=256
//               VGPR (__launch_bounds__(512,2)) + 44 KB LDS = co-resident]
//
// Phase 2 (scan), wave 0 of each block (others exit; no __syncthreads after):
//   y_t = sigmoid(Wo@y_{t-1} + u_t + c). Contraction ||J||_inf <=
//   0.25*||Wo row||_1 ~ 0.28 => WARM=24 from y=0 gives state error
//   <= 0.28^24 ~ 5e-14 (blocks 0-2 replay from t=0 EXACTLY). Serial
//   dependence 2048 -> 32 steps. Lane i owns y_i, broadcast via v_readlane;
//   c finished in double via coalesced b-major loads + butterfly, then
//   shuffle-redistributed (no LDS/barrier needed in this phase).
// ---------------------------------------------------------------------------
#define RL(j) __int_as_float(__builtin_amdgcn_readlane(yi_, j))

#define STEP(bval, ydst)                                                     \
    {                                                                        \
        int yi_ = __float_as_int(y);                                         \
        float a0 = (bval) + cik, a1 = 0.f, a2 = 0.f, a3 = 0.f;               \
        a0 = fmaf(w0,  RL(0),  a0);  a1 = fmaf(w1,  RL(1),  a1);             \
        a2 = fmaf(w2,  RL(2),  a2);  a3 = fmaf(w3,  RL(3),  a3);             \
        a0 = fmaf(w4,  RL(4),  a0);  a1 = fmaf(w5,  RL(5),  a1);             \
        a2 = fmaf(w6,  RL(6),  a2);  a3 = fmaf(w7,  RL(7),  a3);             \
        a0 = fmaf(w8,  RL(8),  a0);  a1 = fmaf(w9,  RL(9),  a1);             \
        a2 = fmaf(w10, RL(10), a2);  a3 = fmaf(w11, RL(11), a3);             \
        a0 = fmaf(w12, RL(12), a0);  a1 = fmaf(w13, RL(13), a1);             \
        a2 = fmaf(w14, RL(14), a2);  a3 = fmaf(w15, RL(15), a3);             \
        a0 = fmaf(w16, RL(16), a0);  a1 = fmaf(w17, RL(17), a1);             \
        a2 = fmaf(w18, RL(18), a2);  a3 = fmaf(w19, RL(19), a3);             \
        a0 = fmaf(w20, RL(20), a0);  a1 = fmaf(w21, RL(21), a1);             \
        a2 = fmaf(w22, RL(22), a2);  a3 = fmaf(w23, RL(23), a3);             \
        a0 = fmaf(w24, RL(24), a0);  a1 = fmaf(w25, RL(25), a1);             \
        a2 = fmaf(w26, RL(26), a2);  a3 = fmaf(w27, RL(27), a3);             \
        float acc_ = (a0 + a1) + (a2 + a3);                                  \
        y = __builtin_amdgcn_rcpf(1.f + __builtin_amdgcn_exp2f(-acc_));      \
        ydst = y;                                                            \
    }

#define SSTEP(n)                                                             \
    {                                                                        \
        int tn_ = (t + 1 < T_FRAMES) ? t + 1 : 0;                            \
        float bn_ = Bmat[(size_t)tn_ * BSTRIDE + bl];   /* prefetch */       \
        STEP(bcur, yb##n)                                                    \
        bcur = bn_; ++t;                                                     \
    }

__global__ __launch_bounds__(512, 2) void fused_kernel(const float* __restrict__ x,
                                                       const float* __restrict__ Uo,
                                                       const float* __restrict__ Co,
                                                       const float* __restrict__ Wo,
                                                       float* __restrict__ cpart,  // [256][32]
                                                       float* __restrict__ Bmat,
                                                       float* __restrict__ out) {
    int tid = threadIdx.x, b = blockIdx.x;
    int wave = tid >> 6, lane = tid & 63;
    __shared__ float  xs[RPB * D_DIM];   // 32 KB: block's 8 x-rows
    __shared__ float4 cs2[512];          // 8 KB: half-colsum staging
    __shared__ float4 cs4[256];          // 4 KB: block-partial colsum

    // ---- scan wave preloads its Wo row NOW (input-ready; hides under prep) ----
    float4 wqa, wqb, wqc, wqd, wqe, wqf, wqg;
    if (wave == 0) {
        const float4* wrow = (const float4*)(Wo + (size_t)((lane < V_DIM) ? lane : 0) * V_DIM);
        wqa = wrow[0]; wqb = wrow[1]; wqc = wrow[2]; wqd = wrow[3];
        wqe = wrow[4]; wqf = wrow[5]; wqg = wrow[6];
    }

    // ---- issue x loads; Uo register loads overlap (independent) ----
    const float4* xb4 = (const float4*)(x + (size_t)b * (RPB * D_DIM));  // 2048 float4
    float4 xl0 = xb4[tid], xl1 = xb4[tid + 512],
           xl2 = xb4[tid + 1024], xl3 = xb4[tid + 1536];

    int nr = (wave < 4) ? 4 : 3;                       // Uo/Co rows this wave owns
    int r0 = (wave < 4) ? wave * 4 : 16 + (wave - 4) * 3;
    float4 u[4][4];                                    // up to 4 rows x 16 floats
#pragma unroll
    for (int q = 0; q < 4; ++q)
        if (q < nr) {
            const float4* u4 = (const float4*)(Uo + (size_t)(r0 + q) * D_DIM);
#pragma unroll
            for (int m = 0; m < 4; ++m) u[q][m] = u4[lane + 64 * m];
        }

    // thread tid covers float4-col (tid&255) of x-rows {h, h+2, h+4, h+6}, h=tid>>8
    ((float4*)xs)[tid]        = xl0;
    ((float4*)xs)[tid + 512]  = xl1;
    ((float4*)xs)[tid + 1024] = xl2;
    ((float4*)xs)[tid + 1536] = xl3;
    float4 cp;
    cp.x = (xl0.x + xl1.x) + (xl2.x + xl3.x);
    cp.y = (xl0.y + xl1.y) + (xl2.y + xl3.y);
    cp.z = (xl0.z + xl1.z) + (xl2.z + xl3.z);
    cp.w = (xl0.w + xl1.w) + (xl2.w + xl3.w);
    cs2[tid] = cp;                       // [h][col] == [tid]
    __syncthreads();
    if (tid < 256) {
        float4 a = cs2[tid], e = cs2[tid + 256];
        cs4[tid] = make_float4(a.x + e.x, a.y + e.y, a.z + e.z, a.w + e.w);
    }
    if (b == 0 && tid < BSTRIDE) Bmat[tid] = 0.f;      // Bmat row 0 = 0
    __syncthreads();

    // ---- cpart[b][i] = Co[i,:] . colsum_partial ----
#pragma unroll
    for (int q = 0; q < 4; ++q)
        if (q < nr) {
            int i = r0 + q;
            const float4* c4 = (const float4*)(Co + (size_t)i * D_DIM);
            float acc = 0.f;
#pragma unroll
            for (int m = 0; m < 4; ++m) {
                float4 a = c4[lane + 64 * m];
                float4 d = cs4[lane + 64 * m];
                acc += a.x * d.x + a.y * d.y + a.z * d.z + a.w * d.w;
            }
#pragma unroll
            for (int off = 32; off > 0; off >>= 1) acc += __shfl_down(acc, off);
            if (lane == 0) cpart[(size_t)b * CSTRIDE + i] = acc;
        }
    if (tid == 0)                        // zero pad cols 28..31 (scan sums them)
        *(float4*)(cpart + (size_t)b * CSTRIDE + V_DIM) = make_float4(0.f, 0.f, 0.f, 0.f);

    // ---- Bmat rows 8b+1 .. 8b+8 ----
#pragma unroll
    for (int r = 0; r < RPB; ++r) {
        int tt = b * RPB + r + 1;
        if (tt < T_FRAMES) {             // only block 255, last row skips (uniform)
            float4 xv[4];
#pragma unroll
            for (int m = 0; m < 4; ++m)
                xv[m] = ((const float4*)xs)[r * 256 + lane + 64 * m];
#pragma unroll
            for (int q = 0; q < 4; ++q)
                if (q < nr) {
                    float acc = 0.f;
#pragma unroll
                    for (int m = 0; m < 4; ++m) {
                        acc = fmaf(u[q][m].x, xv[m].x, acc);
                        acc = fmaf(u[q][m].y, xv[m].y, acc);
                        acc = fmaf(u[q][m].z, xv[m].z, acc);
                        acc = fmaf(u[q][m].w, xv[m].w, acc);
                    }
#pragma unroll
                    for (int off = 32; off > 0; off >>= 1) acc += __shfl_down(acc, off);
                    if (lane == 0) Bmat[(size_t)tt * BSTRIDE + r0 + q] = acc * LOG2E_F;
                }
        }
    }
    // Bmat pads (cols 28..31) stay poison: scan lanes 28-63 compute dead y
    // values never readlane'd or stored — any finite-or-not value is safe.

    cg::this_grid().sync();

    // =================== Phase 2: scan (wave 0 only) ===================
    if (wave != 0) return;               // no __syncthreads below: safe

    // finish c in DOUBLE: lanes split b (8 lanes per i-quad), coalesced
    int q8 = lane & 7, bo = lane >> 3;
    const float4* cp4 = (const float4*)cpart;    // rows of 8 float4
    double d0 = 0.0, d1 = 0.0, d2 = 0.0, d3 = 0.0;
#pragma unroll
    for (int m = 0; m < NBLK / 8; ++m) {         // 32 coalesced 1KB wave-loads
        float4 v = cp4[(size_t)(m * 8 + bo) * (CSTRIDE / 4) + q8];
        d0 += v.x; d1 += v.y; d2 += v.z; d3 += v.w;
    }
#pragma unroll
    for (int off = 8; off < 64; off <<= 1) {     // reduce over bo within i-quad
        d0 += __shfl_xor(d0, off);
        d1 += __shfl_xor(d1, off);
        d2 += __shfl_xor(d2, off);
        d3 += __shfl_xor(d3, off);
    }
    // redistribute: lane i needs quad i>>2 (held by every lane with q8==i>>2),
    // component i&3 — pure shuffles, no LDS/barrier
    int src = lane >> 2;
    double s0 = __shfl(d0, src), s1 = __shfl(d1, src);
    double s2 = __shfl(d2, src), s3 = __shfl(d3, src);
    int comp = lane & 3;
    double cd = (comp == 0) ? s0 : (comp == 1) ? s1 : (comp == 2) ? s2 : s3;
    float cik = (float)cd * LOG2E_F;             // lanes >= 28: dead, finite

    float w0  = wqa.x * LOG2E_F, w1  = wqa.y * LOG2E_F, w2  = wqa.z * LOG2E_F, w3  = wqa.w * LOG2E_F;
    float w4  = wqb.x * LOG2E_F, w5  = wqb.y * LOG2E_F, w6  = wqb.z * LOG2E_F, w7  = wqb.w * LOG2E_F;
    float w8  = wqc.x * LOG2E_F, w9  = wqc.y * LOG2E_F, w10 = wqc.z * LOG2E_F, w11 = wqc.w * LOG2E_F;
    float w12 = wqd.x * LOG2E_F, w13 = wqd.y * LOG2E_F, w14 = wqd.z * LOG2E_F, w15 = wqd.w * LOG2E_F;
    float w16 = wqe.x * LOG2E_F, w17 = wqe.y * LOG2E_F, w18 = wqe.z * LOG2E_F, w19 = wqe.w * LOG2E_F;
    float w20 = wqf.x * LOG2E_F, w21 = wqf.y * LOG2E_F, w22 = wqf.z * LOG2E_F, w23 = wqf.w * LOG2E_F;
    float w24 = wqg.x * LOG2E_F, w25 = wqg.y * LOG2E_F, w26 = wqg.z * LOG2E_F, w27 = wqg.w * LOG2E_F;

    int bl     = lane & (BSTRIDE - 1);
    int tstore = b * CHUNK;                    // first stored step
    int t0     = tstore - WARM; if (t0 < 0) t0 = 0;
    int nwarm  = tstore - t0;                  // 0 / 8 / 16 / 24

    float y    = 0.f;                          // y=0 at t0 (exact for blocks 0-2)
    int   t    = t0;
    float bcur = Bmat[(size_t)t0 * BSTRIDE + bl];

    for (int s = 0; s < nwarm; ++s) {          // warm-up: discard outputs
        float bnext = Bmat[(size_t)(t + 1) * BSTRIDE + bl];
        float dump;
        STEP(bcur, dump)
        (void)dump;
        bcur = bnext; ++t;
    }

    float yb0, yb1, yb2, yb3, yb4, yb5, yb6, yb7;
    SSTEP(0) SSTEP(1) SSTEP(2) SSTEP(3)
    SSTEP(4) SSTEP(5) SSTEP(6) SSTEP(7)

    if (lane < V_DIM) {                        // burst all stores at the end
        float* op = out + (size_t)tstore * V_DIM + lane;
        op[0 * V_DIM] = yb0; op[1 * V_DIM] = yb1;
        op[2 * V_DIM] = yb2; op[3 * V_DIM] = yb3;
        op[4 * V_DIM] = yb4; op[5 * V_DIM] = yb5;
        op[6 * V_DIM] = yb6; op[7 * V_DIM] = yb7;
    }
}

// ---------------------------------------------------------------------------
extern "C" void kernel_launch(void* const* d_in, const int* in_sizes, int n_in,
                              void* d_out, int out_size, void* d_ws, size_t ws_size,
                              hipStream_t stream) {
    const float* x  = (const float*)d_in[0];
    // d_in[1]=Wa, d_in[2]=Ua, d_in[3]=Va: dead code (softmax over size-1 axis)
    const float* Wo = (const float*)d_in[4];
    const float* Uo = (const float*)d_in[5];
    const float* Co = (const float*)d_in[6];
    float* out = (float*)d_out;

    float* W     = (float*)d_ws;
    float* cpart = W;                       // 256*32 floats (32 KB), b-major
    float* Bmat  = W + NBLK * CSTRIDE;      // 2048*32 floats (256 KB)

    // ONE cooperative dispatch (256 blocks x 512 thr = 1 block/CU, co-resident)
    void* args[] = {(void*)&x, (void*)&Uo, (void*)&Co, (void*)&Wo,
                    (void*)&cpart, (void*)&Bmat, (void*)&out};
    hipLaunchCooperativeKernel((void*)fused_kernel, dim3(NBLK), dim3(512),
                               args, 0, stream);
}

// Round 6
// 90.899 us; speedup vs baseline: 1.4013x; 1.4013x over previous
//
#include <hip/hip_runtime.h>

#define T_FRAMES 2048
#define D_DIM    1024
#define V_DIM    28
#define BSTRIDE  32                 // Bmat row stride (padded, pow2)
#define CSTRIDE  32                 // cpart row stride (padded, pow2)
#define LOG2E_F  1.44269504088896f

#define CHUNK    8                  // stored steps per scan block
#define WARM     24                 // warm-up steps (contraction ~0.28^24 ~ 5e-14)
#define NCHUNK   (T_FRAMES / CHUNK) // 256 scan blocks
#define RPB      8                  // x rows per prep block
#define NB_PREP  (T_FRAMES / RPB)   // 256 prep blocks x 512 thr = 2 waves/SIMD

// ---------------------------------------------------------------------------
// R5 lesson (measured): cg::grid.sync() on MI355X cost ~35us of idle
// (fused_kernel 41.9us, VALUBusy 7.5%) — an order of magnitude worse than
// the ~2us dependent-dispatch gap it replaced. Back to 2 dispatches.
//
// Kernel 1 (prep), 256 blocks x 512 threads, block b owns x rows 8b..8b+7:
//   - stage 8 rows in LDS (32 KB) while folding block-partial colsum
//     (x read ONCE: 8 MB),
//   - cpart[b][i] = Co[i,:] . partial_colsum  (b-major, pads zeroed; scan
//     finishes c in DOUBLE — fp32 finish cost absmax 4e-3 in R3),
//   - Bmat[8b+r+1][i] = (Uo[i,:] . x[8b+r]) * log2e. Waves 0-3 hold 4 Uo
//     rows in regs, waves 4-7 hold 3 (28 total), reused across 8 x-rows:
//     Uo+Co L2 traffic 256 x 229 KB = 59 MB (R4: 115 MB) at the same
//     2 waves/SIMD TLP (R2's RPB=8 @ 256thr was 1 wave/SIMD: latency-bound).
// ---------------------------------------------------------------------------
__global__ __launch_bounds__(512) void prep_kernel(const float* __restrict__ x,
                                                   const float* __restrict__ Uo,
                                                   const float* __restrict__ Co,
                                                   float* __restrict__ cpart,  // [256][32]
                                                   float* __restrict__ Bmat) {
    int tid = threadIdx.x, b = blockIdx.x;
    int wave = tid >> 6, lane = tid & 63;
    __shared__ float  xs[RPB * D_DIM];   // 32 KB: block's 8 x-rows
    __shared__ float4 cs2[512];          // 8 KB: half-colsum staging
    __shared__ float4 cs4[256];          // 4 KB: block-partial colsum

    // ---- issue x loads; Uo register loads overlap (independent) ----
    const float4* xb4 = (const float4*)(x + (size_t)b * (RPB * D_DIM));  // 2048 float4
    float4 xl0 = xb4[tid], xl1 = xb4[tid + 512],
           xl2 = xb4[tid + 1024], xl3 = xb4[tid + 1536];

    int nr = (wave < 4) ? 4 : 3;                       // Uo/Co rows this wave owns
    int r0 = (wave < 4) ? wave * 4 : 16 + (wave - 4) * 3;
    float4 u[4][4];                                    // up to 4 rows x 16 floats
#pragma unroll
    for (int q = 0; q < 4; ++q)
        if (q < nr) {
            const float4* u4 = (const float4*)(Uo + (size_t)(r0 + q) * D_DIM);
#pragma unroll
            for (int m = 0; m < 4; ++m) u[q][m] = u4[lane + 64 * m];
        }

    // thread tid covers float4-col (tid&255) of x-rows {h, h+2, h+4, h+6}, h=tid>>8
    ((float4*)xs)[tid]        = xl0;
    ((float4*)xs)[tid + 512]  = xl1;
    ((float4*)xs)[tid + 1024] = xl2;
    ((float4*)xs)[tid + 1536] = xl3;
    float4 cp;
    cp.x = (xl0.x + xl1.x) + (xl2.x + xl3.x);
    cp.y = (xl0.y + xl1.y) + (xl2.y + xl3.y);
    cp.z = (xl0.z + xl1.z) + (xl2.z + xl3.z);
    cp.w = (xl0.w + xl1.w) + (xl2.w + xl3.w);
    cs2[tid] = cp;                       // [parity h][col] == [tid]
    __syncthreads();
    if (tid < 256) {
        float4 a = cs2[tid], e = cs2[tid + 256];
        cs4[tid] = make_float4(a.x + e.x, a.y + e.y, a.z + e.z, a.w + e.w);
    }
    if (b == 0 && tid < BSTRIDE) Bmat[tid] = 0.f;      // Bmat row 0 = 0
    __syncthreads();

    // ---- cpart[b][i] = Co[i,:] . colsum_partial ----
#pragma unroll
    for (int q = 0; q < 4; ++q)
        if (q < nr) {
            int i = r0 + q;
            const float4* c4 = (const float4*)(Co + (size_t)i * D_DIM);
            float acc = 0.f;
#pragma unroll
            for (int m = 0; m < 4; ++m) {
                float4 a = c4[lane + 64 * m];
                float4 d = cs4[lane + 64 * m];
                acc += a.x * d.x + a.y * d.y + a.z * d.z + a.w * d.w;
            }
#pragma unroll
            for (int off = 32; off > 0; off >>= 1) acc += __shfl_down(acc, off);
            if (lane == 0) cpart[(size_t)b * CSTRIDE + i] = acc;
        }
    if (tid == 0)                        // zero pad cols 28..31 (scan sums them)
        *(float4*)(cpart + (size_t)b * CSTRIDE + V_DIM) = make_float4(0.f, 0.f, 0.f, 0.f);

    // ---- Bmat rows 8b+1 .. 8b+8 ----
#pragma unroll
    for (int r = 0; r < RPB; ++r) {
        int tt = b * RPB + r + 1;
        if (tt < T_FRAMES) {             // only block 255, last row skips (uniform)
            float4 xv[4];
#pragma unroll
            for (int m = 0; m < 4; ++m)
                xv[m] = ((const float4*)xs)[r * 256 + lane + 64 * m];
#pragma unroll
            for (int q = 0; q < 4; ++q)
                if (q < nr) {
                    float acc = 0.f;
#pragma unroll
                    for (int m = 0; m < 4; ++m) {
                        acc = fmaf(u[q][m].x, xv[m].x, acc);
                        acc = fmaf(u[q][m].y, xv[m].y, acc);
                        acc = fmaf(u[q][m].z, xv[m].z, acc);
                        acc = fmaf(u[q][m].w, xv[m].w, acc);
                    }
#pragma unroll
                    for (int off = 32; off > 0; off >>= 1) acc += __shfl_down(acc, off);
                    if (lane == 0) Bmat[(size_t)tt * BSTRIDE + r0 + q] = acc * LOG2E_F;
                }
        }
    }
    // Bmat pads (cols 28..31) stay poison: scan lanes 28-63 compute dead y
    // values never readlane'd or stored — any value is safe.
}

// ---------------------------------------------------------------------------
// Kernel 2: chunked-parallel scan of y_t = sigmoid(Wo@y_{t-1} + u_t + c).
// Contraction: ||J||_inf <= 0.25*||Wo row||_1 ~ 0.28 => WARM=24 warm-up
// steps from y=0 give state error <= 0.28^24 ~ 5e-14 (blocks 0-2 replay
// from t=0 EXACTLY). Serial dependence 2048 -> 32 steps. One wave/block,
// lane i owns y_i, broadcast via v_readlane; c finished in DOUBLE via
// coalesced b-major loads + butterfly + shuffle redistribute (no LDS).
// ---------------------------------------------------------------------------
#define RL(j) __int_as_float(__builtin_amdgcn_readlane(yi_, j))

#define STEP(bval, ydst)                                                     \
    {                                                                        \
        int yi_ = __float_as_int(y);                                         \
        float a0 = (bval) + cik, a1 = 0.f, a2 = 0.f, a3 = 0.f;               \
        a0 = fmaf(w0,  RL(0),  a0);  a1 = fmaf(w1,  RL(1),  a1);             \
        a2 = fmaf(w2,  RL(2),  a2);  a3 = fmaf(w3,  RL(3),  a3);             \
        a0 = fmaf(w4,  RL(4),  a0);  a1 = fmaf(w5,  RL(5),  a1);             \
        a2 = fmaf(w6,  RL(6),  a2);  a3 = fmaf(w7,  RL(7),  a3);             \
        a0 = fmaf(w8,  RL(8),  a0);  a1 = fmaf(w9,  RL(9),  a1);             \
        a2 = fmaf(w10, RL(10), a2);  a3 = fmaf(w11, RL(11), a3);             \
        a0 = fmaf(w12, RL(12), a0);  a1 = fmaf(w13, RL(13), a1);             \
        a2 = fmaf(w14, RL(14), a2);  a3 = fmaf(w15, RL(15), a3);             \
        a0 = fmaf(w16, RL(16), a0);  a1 = fmaf(w17, RL(17), a1);             \
        a2 = fmaf(w18, RL(18), a2);  a3 = fmaf(w19, RL(19), a3);             \
        a0 = fmaf(w20, RL(20), a0);  a1 = fmaf(w21, RL(21), a1);             \
        a2 = fmaf(w22, RL(22), a2);  a3 = fmaf(w23, RL(23), a3);             \
        a0 = fmaf(w24, RL(24), a0);  a1 = fmaf(w25, RL(25), a1);             \
        a2 = fmaf(w26, RL(26), a2);  a3 = fmaf(w27, RL(27), a3);             \
        float acc_ = (a0 + a1) + (a2 + a3);                                  \
        y = __builtin_amdgcn_rcpf(1.f + __builtin_amdgcn_exp2f(-acc_));      \
        ydst = y;                                                            \
    }

#define SSTEP(n)                                                             \
    {                                                                        \
        int tn_ = (t + 1 < T_FRAMES) ? t + 1 : 0;                            \
        float bn_ = Bmat[(size_t)tn_ * BSTRIDE + bl];   /* prefetch */       \
        STEP(bcur, yb##n)                                                    \
        bcur = bn_; ++t;                                                     \
    }

__global__ __launch_bounds__(64, 1) void scan_kernel(const float* __restrict__ Bmat,
                                                     const float* __restrict__ cpart,
                                                     const float* __restrict__ Wo,
                                                     float* __restrict__ out) {
    int lane = threadIdx.x;
    bool act = lane < V_DIM;
    int bl   = lane & (BSTRIDE - 1);

    // ---- Wo row -> registers, float4 (address-clamped for dead lanes) ----
    const float4* wrow = (const float4*)(Wo + (size_t)(act ? lane : 0) * V_DIM);
    float4 wqa = wrow[0], wqb = wrow[1], wqc = wrow[2], wqd = wrow[3];
    float4 wqe = wrow[4], wqf = wrow[5], wqg = wrow[6];

    // ---- finish c in DOUBLE: lanes split b (8 lanes per i-quad) ----
    int q8 = lane & 7, bo = lane >> 3;
    const float4* cp4 = (const float4*)cpart;    // rows of 8 float4
    double d0 = 0.0, d1 = 0.0, d2 = 0.0, d3 = 0.0;
#pragma unroll
    for (int m = 0; m < NB_PREP / 8; ++m) {      // 32 coalesced 1KB wave-loads
        float4 v = cp4[(size_t)(m * 8 + bo) * (CSTRIDE / 4) + q8];
        d0 += v.x; d1 += v.y; d2 += v.z; d3 += v.w;
    }
#pragma unroll
    for (int off = 8; off < 64; off <<= 1) {     // reduce over bo within i-quad
        d0 += __shfl_xor(d0, off);
        d1 += __shfl_xor(d1, off);
        d2 += __shfl_xor(d2, off);
        d3 += __shfl_xor(d3, off);
    }
    // redistribute: lane i needs quad i>>2 component i&3 — pure shuffles
    int src = lane >> 2;
    double s0 = __shfl(d0, src), s1 = __shfl(d1, src);
    double s2 = __shfl(d2, src), s3 = __shfl(d3, src);
    int comp = lane & 3;
    double cd = (comp == 0) ? s0 : (comp == 1) ? s1 : (comp == 2) ? s2 : s3;
    float cik = (float)cd * LOG2E_F;             // lanes >= 28: dead, finite

    float w0  = wqa.x * LOG2E_F, w1  = wqa.y * LOG2E_F, w2  = wqa.z * LOG2E_F, w3  = wqa.w * LOG2E_F;
    float w4  = wqb.x * LOG2E_F, w5  = wqb.y * LOG2E_F, w6  = wqb.z * LOG2E_F, w7  = wqb.w * LOG2E_F;
    float w8  = wqc.x * LOG2E_F, w9  = wqc.y * LOG2E_F, w10 = wqc.z * LOG2E_F, w11 = wqc.w * LOG2E_F;
    float w12 = wqd.x * LOG2E_F, w13 = wqd.y * LOG2E_F, w14 = wqd.z * LOG2E_F, w15 = wqd.w * LOG2E_F;
    float w16 = wqe.x * LOG2E_F, w17 = wqe.y * LOG2E_F, w18 = wqe.z * LOG2E_F, w19 = wqe.w * LOG2E_F;
    float w20 = wqf.x * LOG2E_F, w21 = wqf.y * LOG2E_F, w22 = wqf.z * LOG2E_F, w23 = wqf.w * LOG2E_F;
    float w24 = wqg.x * LOG2E_F, w25 = wqg.y * LOG2E_F, w26 = wqg.z * LOG2E_F, w27 = wqg.w * LOG2E_F;

    int tstore = blockIdx.x * CHUNK;           // first stored step
    int t0     = tstore - WARM; if (t0 < 0) t0 = 0;
    int nwarm  = tstore - t0;                  // 0 / 8 / 16 / 24

    float y    = 0.f;                          // y=0 at t0 (exact for blocks 0-2)
    int   t    = t0;
    float bcur = Bmat[(size_t)t0 * BSTRIDE + bl];

    for (int s = 0; s < nwarm; ++s) {          // warm-up: discard outputs
        float bnext = Bmat[(size_t)(t + 1) * BSTRIDE + bl];
        float dump;
        STEP(bcur, dump)
        (void)dump;
        bcur = bnext; ++t;
    }

    float yb0, yb1, yb2, yb3, yb4, yb5, yb6, yb7;
    SSTEP(0) SSTEP(1) SSTEP(2) SSTEP(3)
    SSTEP(4) SSTEP(5) SSTEP(6) SSTEP(7)

    if (act) {                                 // burst all stores at the end
        float* op = out + (size_t)tstore * V_DIM + lane;
        op[0 * V_DIM] = yb0; op[1 * V_DIM] = yb1;
        op[2 * V_DIM] = yb2; op[3 * V_DIM] = yb3;
        op[4 * V_DIM] = yb4; op[5 * V_DIM] = yb5;
        op[6 * V_DIM] = yb6; op[7 * V_DIM] = yb7;
    }
}

// ---------------------------------------------------------------------------
extern "C" void kernel_launch(void* const* d_in, const int* in_sizes, int n_in,
                              void* d_out, int out_size, void* d_ws, size_t ws_size,
                              hipStream_t stream) {
    const float* x  = (const float*)d_in[0];
    // d_in[1]=Wa, d_in[2]=Ua, d_in[3]=Va: dead code (softmax over size-1 axis)
    const float* Wo = (const float*)d_in[4];
    const float* Uo = (const float*)d_in[5];
    const float* Co = (const float*)d_in[6];
    float* out = (float*)d_out;

    float* W     = (float*)d_ws;
    float* cpart = W;                       // 256*32 floats (32 KB), b-major
    float* Bmat  = W + NB_PREP * CSTRIDE;   // 2048*32 floats (256 KB)

    // 2 dispatches (memset-free; R5 showed grid.sync costs ~35us — never again)
    prep_kernel<<<NB_PREP, 512, 0, stream>>>(x, Uo, Co, cpart, Bmat);
    scan_kernel<<<NCHUNK,  64,  0, stream>>>(Bmat, cpart, Wo, out);
}